// Round 4
// baseline (291.365 us; speedup 1.0000x reference)
//
#include <hip/hip_runtime.h>
#include <cstdint>

typedef unsigned short ushort_t;
typedef __bf16 bf16x8 __attribute__((ext_vector_type(8)));
typedef ushort_t u16x8 __attribute__((ext_vector_type(8)));
typedef float f32x4 __attribute__((ext_vector_type(4)));
typedef uint32_t u32x4 __attribute__((ext_vector_type(4)));

#define RMS_EPS 1.1920928955078125e-07f
// B=8 T=4096 C=256 Wh=1024 E=8 K=2 ; tokens NT=32768, pairs NP=65536

__device__ __forceinline__ ushort_t f2bf(float f) {
  uint32_t u = __builtin_bit_cast(uint32_t, f);
  u += 0x7fffu + ((u >> 16) & 1u);   // RNE
  return (ushort_t)(u >> 16);
}

__device__ __forceinline__ void g2l16(const ushort_t* g, ushort_t* l) {
  __builtin_amdgcn_global_load_lds(
      (const __attribute__((address_space(1))) uint32_t*)g,
      (__attribute__((address_space(3))) uint32_t*)l, 16, 0, 0);
}

__device__ __forceinline__ f32x4 mfma32(bf16x8 a, bf16x8 b, f32x4 c) {
  return __builtin_amdgcn_mfma_f32_16x16x32_bf16(a, b, c, 0, 0, 0);
}

// GELU via odd-poly erf approx (validated round 3, absmax 8.0 vs thr 41.6):
// gelu(v) = 0.5*v*(1 + E(clamp(v,±2.9))), 8 full-rate VALU, no transcendentals.
__device__ __forceinline__ float gelu1(float v) {
  float vc = fminf(fmaxf(v, -2.9f), 2.9f);   // v_med3
  float x2 = vc * vc;
  float p = fmaf(-0.000414256f, x2, 0.0107517f);
  p = fmaf(p, x2, -0.1136149f);
  p = fmaf(p, x2, 0.786301f);
  float E = vc * p;
  float t = 0.5f * v;
  return fmaf(t, E, t);
}

// ---- fused pre-pass: rmsnorm (blocks 0..8191) | pack_w (8192..8703) |
//      route (8704..8959). One dispatch instead of three (launch overhead
//      was ~100us of the 224us total; the three are mutually independent).
__global__ __launch_bounds__(256) void fused_pre(
    const float* __restrict__ x, const float* __restrict__ rw,
    ushort_t* __restrict__ xn,
    const float* __restrict__ W1, const float* __restrict__ W2,
    ushort_t* __restrict__ w1f, ushort_t* __restrict__ w2f,
    const int* __restrict__ eids, int* __restrict__ cnt,
    int* __restrict__ lists) {
  __shared__ ushort_t tile[64][130];
  __shared__ int lcnt[8], lbase[8];
  int bid = blockIdx.x;
  int t = threadIdx.x;

  if (bid < 8192) {
    // ---- RMSNorm + cast to bf16: one wave per token ----
    int token = bid * 4 + (t >> 6);
    int lane = t & 63;
    const float4* row = reinterpret_cast<const float4*>(x + (size_t)token * 256);
    float4 v = row[lane];
    float s = v.x * v.x + v.y * v.y + v.z * v.z + v.w * v.w;
#pragma unroll
    for (int off = 1; off < 64; off <<= 1) s += __shfl_xor(s, off);
    float inv = rsqrtf(s * (1.0f / 256.0f) + RMS_EPS);
    const float4* wr = reinterpret_cast<const float4*>(rw);
    float4 wv = wr[lane];
    ushort4 o;
    o.x = f2bf(v.x * inv * wv.x);
    o.y = f2bf(v.y * inv * wv.y);
    o.z = f2bf(v.z * inv * wv.z);
    o.w = f2bf(v.w * inv * wv.w);
    *reinterpret_cast<ushort4*>(xn + (size_t)token * 256 + lane * 4) = o;
  } else if (bid < 8704) {
    // ---- pack W1/W2 into MFMA fragment order via LDS tile ----
    // W1 (K=32 frags): unit = e*32768 + ch*1024 + kk*128 + nt*64 + lane;
    //   elem j = W1[e][kk*32+quad*8+j][ch*32+nt*16+l16]
    // W2 (half-interleaved, A-operand of concat-K32 GEMM2):
    //   unit U = ((e*32+ch)*16+ct)*64 + lane ;
    //   elem j   = W2[e][ch*32 +  0 + quad*4+j][ct*16+l16]
    //   elem 4+j = W2[e][ch*32 + 16 + quad*4+j][ct*16+l16]
    int b = bid - 8192;
    int isW2 = b >= 256;
    const float* src; ushort_t* dst; int e, kt, wt, rs;
    if (!isW2) { e = b >> 5; kt = (b >> 3) & 3; wt = b & 7; src = W1; dst = w1f; rs = 1024; }
    else { b -= 256; e = b >> 5; kt = (b >> 1) & 15; wt = b & 1; src = W2; dst = w2f; rs = 256; }
    int k0 = kt * 64, c0 = wt * 128;
    const float* sb = src + ((size_t)e << 18) + (size_t)k0 * rs + c0;
#pragma unroll
    for (int i = 0; i < 8; ++i) {
      int f = i * 1024 + t * 4;          // [0,8192)
      int r = f >> 7, c = f & 127;
      float4 v = *reinterpret_cast<const float4*>(sb + (size_t)r * rs + c);
      ushort2 lo, hi;
      lo.x = f2bf(v.x); lo.y = f2bf(v.y); hi.x = f2bf(v.z); hi.y = f2bf(v.w);
      *reinterpret_cast<ushort2*>(&tile[r][c]) = lo;
      *reinterpret_cast<ushort2*>(&tile[r][c + 2]) = hi;
    }
    __syncthreads();
    int lane = t & 63, l16 = lane & 15, quad = lane >> 4;
    int wave = t >> 6;
    if (!isW2) {
#pragma unroll
      for (int p = 0; p < 4; ++p) {
        int u = p * 256 + t;               // [0,1024)
        int kk2 = (u >> 9) & 1;
        int rr = kk2 * 32 + quad * 8;
        int nt = (u >> 6) & 1, chL = (u >> 7) & 3;
        int cc = chL * 32 + nt * 16 + l16;
        u16x8 o;
#pragma unroll
        for (int j = 0; j < 8; ++j) o[j] = tile[rr + j][cc];
        size_t U = ((size_t)e * 32768) + (size_t)(wt * 4 + chL) * 1024 + (kt * 2 + kk2) * 128 + nt * 64 + lane;
        *reinterpret_cast<u16x8*>(dst + U * 8) = o;
      }
    } else {
#pragma unroll
      for (int p = 0; p < 4; ++p) {
        int u = p * 4 + wave;              // [0,16): chL(2) x ctL(8)
        int chL = u >> 3, ctL = u & 7;
        int cc = ctL * 16 + l16;
        u16x8 o;
#pragma unroll
        for (int j = 0; j < 4; ++j) o[j] = tile[chL * 32 + quad * 4 + j][cc];
#pragma unroll
        for (int j = 0; j < 4; ++j) o[4 + j] = tile[chL * 32 + 16 + quad * 4 + j][cc];
        size_t U = (((size_t)(e * 32 + kt * 2 + chL) * 16) + (wt * 8 + ctL)) * 64 + lane;
        *reinterpret_cast<u16x8*>(dst + U * 8) = o;
      }
    }
  } else {
    // ---- route (t,k) pairs into per-expert lists ----
    if (t < 8) lcnt[t] = 0;
    __syncthreads();
    int p = (bid - 8704) * 256 + t;
    int e = eids[p];
    int lpos = atomicAdd(&lcnt[e], 1);
    __syncthreads();
    if (t < 8) lbase[t] = atomicAdd(&cnt[t], lcnt[t]);
    __syncthreads();
    lists[e * 65536 + lbase[e] + lpos] = p;
  }
}

// ---- fused expert MLP ----
// 8-wave (512-thread) blocks: 256 pairs/block, each wave 32 tokens (mt=2).
// mt=2 halves LDS weight-read traffic per FLOP vs round 3 (each W1/W2
// fragment read feeds 2 MFMAs). 8 co-resident waves = 2 waves/SIMD
// GUARANTEED by block residency (no multi-block scheduling gamble).
// Regs/wave ~ acc 128 AGPR + afr 64 VGPR + ~45 temps ~= 240 <= 256.
// LDS 48KB. Grid 264 = 8 x 33 (bijective XCD swizzle, ~1.03 blocks/CU).
// LDS model: 32 chunks x (262KB reads + 32KB writes) ~= 9.4MB/CU -> ~46us.
__global__ __launch_bounds__(512, 2) void moe_mlp(
    const ushort_t* __restrict__ xn,   // [32768][256] bf16
    const ushort_t* __restrict__ w1f,  // [8][32][8][2][64][8]
    const ushort_t* __restrict__ w2f,  // [8][32][16][64][8]
    const float* __restrict__ b1,      // [8][1024]
    const float* __restrict__ b2,      // [8][256]
    const int* __restrict__ cnt,       // [8]
    const int* __restrict__ lists,     // [8][65536]
    float* __restrict__ out)           // [65536][256]
{
  __shared__ __align__(16) ushort_t w1b[2][8192];   // 2 x 16KB
  __shared__ __align__(16) ushort_t w2b[8192];      // 1 x 16KB

  // bijective XCD swizzle; gridDim.x = 264 = 8*33 exactly
  int cpx = gridDim.x >> 3;
  int flat = (blockIdx.x & 7) * cpx + (blockIdx.x >> 3);

  int e = -1, tile = 0, accum = 0, n_e = 0;
#pragma unroll
  for (int i = 0; i < 8; ++i) {
    int c = cnt[i];
    int ti = (c + 255) >> 8;
    if (e < 0 && flat < accum + ti) { e = i; tile = flat - accum; n_e = c; }
    accum += ti;
  }
  if (e < 0) return;
  int start = tile * 256;

  int tid = threadIdx.x;
  int wave = tid >> 6, lane = tid & 63, l16 = lane & 15, quad = lane >> 4;

  const ushort_t* w1e = w1f + ((size_t)e << 18);
  const ushort_t* w2e = w2f + ((size_t)e << 18);
  const int* le = lists + e * 65536;

  // stage W1(0) into buffer 0 (16 x 1KB units across 8 waves)
#pragma unroll
  for (int j = 0; j < 2; ++j) {
    int p = j * 8 + wave;
    g2l16(w1e + p * 512 + lane * 8, &w1b[0][p * 512]);
  }

  // A fragments: 2 m-tiles (32 tokens) x full K=256, resident (64 VGPR).
  // pr/gi intentionally NOT kept live (recomputed in epilogue) - reg diet.
  bf16x8 afr[2][8];
  {
    int gi0 = start + wave * 32 + l16;
    int pr0 = le[(gi0 < n_e) ? gi0 : 0];
    int pr1 = le[(gi0 + 16 < n_e) ? gi0 + 16 : 0];
    const u32x4* ar0 = reinterpret_cast<const u32x4*>(xn + (size_t)(pr0 >> 1) * 256);
    const u32x4* ar1 = reinterpret_cast<const u32x4*>(xn + (size_t)(pr1 >> 1) * 256);
#pragma unroll
    for (int kk = 0; kk < 8; ++kk) {
      afr[0][kk] = __builtin_bit_cast(bf16x8, ar0[kk * 4 + quad]);
      afr[1][kk] = __builtin_bit_cast(bf16x8, ar1[kk * 4 + quad]);
    }
  }

  f32x4 acc[2][16];
#pragma unroll
  for (int mt = 0; mt < 2; ++mt)
#pragma unroll
    for (int ct = 0; ct < 16; ++ct) acc[mt][ct] = (f32x4){0.f, 0.f, 0.f, 0.f};

  const float* b1e = b1 + e * 1024;

  for (int ch = 0; ch < 32; ++ch) {
    int cur = ch & 1;
    __syncthreads();   // W1(ch) staged+visible; w2b free (GEMM2(ch-1) done)

    // stage W2(ch) -> single buffer (lands under GEMM1+GELU)
    {
      const ushort_t* n2 = w2e + ch * 8192;
#pragma unroll
      for (int j = 0; j < 2; ++j) {
        int p = j * 8 + wave;
        g2l16(n2 + p * 512 + lane * 8, &w2b[p * 512]);
      }
    }
    // stage W1(ch+1) -> alternate buffer
    if (ch + 1 < 32) {
      const ushort_t* n1 = w1e + (ch + 1) * 8192;
#pragma unroll
      for (int j = 0; j < 2; ++j) {
        int p = j * 8 + wave;
        g2l16(n1 + p * 512 + lane * 8, &w1b[cur ^ 1][p * 512]);
      }
    }

    // GEMM1 (swapped): hT ; 4 independent chains x 8 deep; each W1 frag
    // read (b128) feeds 2 MFMAs (mt=2 amortization — the point of this build)
    const ushort_t* l1 = w1b[cur];
    f32x4 ht00 = (f32x4){0.f, 0.f, 0.f, 0.f};
    f32x4 ht01 = (f32x4){0.f, 0.f, 0.f, 0.f};
    f32x4 ht10 = (f32x4){0.f, 0.f, 0.f, 0.f};
    f32x4 ht11 = (f32x4){0.f, 0.f, 0.f, 0.f};
#pragma unroll
    for (int kk = 0; kk < 8; ++kk) {
      bf16x8 wA = *reinterpret_cast<const bf16x8*>(l1 + ((kk * 2 + 0) * 64 + lane) * 8);
      bf16x8 wB = *reinterpret_cast<const bf16x8*>(l1 + ((kk * 2 + 1) * 64 + lane) * 8);
      ht00 = mfma32(wA, afr[0][kk], ht00);
      ht10 = mfma32(wA, afr[1][kk], ht10);
      ht01 = mfma32(wB, afr[0][kk], ht01);
      ht11 = mfma32(wB, afr[1][kk], ht11);
    }

    // biases loaded late (short live range)
    int w0 = ch * 32;
    f32x4 bia0 = *reinterpret_cast<const f32x4*>(b1e + w0 + quad * 4);
    f32x4 bia1 = *reinterpret_cast<const f32x4*>(b1e + w0 + 16 + quad * 4);

    // GELU + bf16 pack in registers. elems 0-3 = nt0 half (w=w0+quad*4+r),
    // elems 4-7 = nt1 half — matches W2 frag interleave (round-2 verified).
    u16x8 hp0, hp1;
#pragma unroll
    for (int rr = 0; rr < 4; ++rr) {
      hp0[rr]     = f2bf(gelu1(ht00[rr] + bia0[rr]));
      hp0[4 + rr] = f2bf(gelu1(ht01[rr] + bia1[rr]));
      hp1[rr]     = f2bf(gelu1(ht10[rr] + bia0[rr]));
      hp1[4 + rr] = f2bf(gelu1(ht11[rr] + bia1[rr]));
    }
    bf16x8 hF0 = __builtin_bit_cast(bf16x8, hp0);
    bf16x8 hF1 = __builtin_bit_cast(bf16x8, hp1);

    __syncthreads();   // W2(ch) staged+visible (all waves)

    // GEMM2: yT[32 tok x 256] += W2^T . hT via K=32 MFMA; each W2 frag
    // read feeds 2 MFMAs
#pragma unroll
    for (int ct = 0; ct < 16; ++ct) {
      bf16x8 wq = *reinterpret_cast<const bf16x8*>(w2b + (ct * 64 + lane) * 8);
      acc[0][ct] = mfma32(wq, hF0, acc[0][ct]);
      acc[1][ct] = mfma32(wq, hF1, acc[1][ct]);
    }
  }

  // epilogue: +b2, masked float4 store; pr re-read from lists (not kept live)
  const float* b2e = b2 + e * 256;
#pragma unroll
  for (int mt = 0; mt < 2; ++mt) {
    int gi = start + wave * 32 + mt * 16 + l16;
    if (gi < n_e) {
      int pr = le[gi];
      float* orow = out + (size_t)pr * 256;
#pragma unroll
      for (int ct = 0; ct < 16; ++ct) {
        f32x4 bv = *reinterpret_cast<const f32x4*>(b2e + ct * 16 + quad * 4);
        f32x4 o = acc[mt][ct] + bv;
        *reinterpret_cast<f32x4*>(orow + ct * 16 + quad * 4) = o;
      }
    }
  }
}

extern "C" void kernel_launch(void* const* d_in, const int* in_sizes, int n_in,
                              void* d_out, int out_size, void* d_ws, size_t ws_size,
                              hipStream_t stream) {
  const float* x  = (const float*)d_in[0];
  const float* rw = (const float*)d_in[1];
  const float* W1 = (const float*)d_in[2];
  const float* b1 = (const float*)d_in[3];
  const float* W2 = (const float*)d_in[4];
  const float* b2 = (const float*)d_in[5];
  const int* eids = (const int*)d_in[6];
  float* out = (float*)d_out;

  char* ws = (char*)d_ws;
  ushort_t* xn  = (ushort_t*)(ws);              // 16,777,216 B
  ushort_t* w1f = (ushort_t*)(ws + 16777216);   //  4,194,304 B
  ushort_t* w2f = (ushort_t*)(ws + 20971520);   //  4,194,304 B
  int* cnt      = (int*)(ws + 25165824);        //  256 B (8 used)
  int* lists    = (int*)(ws + 25166080);        //  2,097,152 B

  hipMemsetAsync(cnt, 0, 8 * sizeof(int), stream);
  // one fused pre-pass dispatch: rmsnorm (8192) + pack_w (512) + route (256)
  fused_pre<<<8960, 256, 0, stream>>>(x, rw, xn, W1, W2, w1f, w2f, eids, cnt, lists);
  // max tiles = sum_e ceil(c_e/256) <= 65536/256 + 8 = 264 (= 8*33)
  moe_mlp<<<264, 512, 0, stream>>>(xn, w1f, w2f, b1, b2, cnt, lists, out);
}

// Round 5
// 268.287 us; speedup vs baseline: 1.0860x; 1.0860x over previous
//
#include <hip/hip_runtime.h>
#include <cstdint>

typedef unsigned short ushort_t;
typedef __bf16 bf16x8 __attribute__((ext_vector_type(8)));
typedef ushort_t u16x8 __attribute__((ext_vector_type(8)));
typedef float f32x4 __attribute__((ext_vector_type(4)));
typedef uint32_t u32x4 __attribute__((ext_vector_type(4)));

#define RMS_EPS 1.1920928955078125e-07f
// B=8 T=4096 C=256 Wh=1024 E=8 K=2 ; tokens NT=32768, pairs NP=65536

__device__ __forceinline__ ushort_t f2bf(float f) {
  uint32_t u = __builtin_bit_cast(uint32_t, f);
  u += 0x7fffu + ((u >> 16) & 1u);   // RNE
  return (ushort_t)(u >> 16);
}

__device__ __forceinline__ void g2l16(const ushort_t* g, ushort_t* l) {
  __builtin_amdgcn_global_load_lds(
      (const __attribute__((address_space(1))) uint32_t*)g,
      (__attribute__((address_space(3))) uint32_t*)l, 16, 0, 0);
}

__device__ __forceinline__ f32x4 mfma32(bf16x8 a, bf16x8 b, f32x4 c) {
  return __builtin_amdgcn_mfma_f32_16x16x32_bf16(a, b, c, 0, 0, 0);
}

// GELU via odd-poly erf approx (validated r3/r4, absmax 8.0 vs thr 41.6):
// gelu(v) = 0.5*v*(1 + E(clamp(v,±2.9))), 8 full-rate VALU, no transcendentals.
__device__ __forceinline__ float gelu1(float v) {
  float vc = fminf(fmaxf(v, -2.9f), 2.9f);   // v_med3
  float x2 = vc * vc;
  float p = fmaf(-0.000414256f, x2, 0.0107517f);
  p = fmaf(p, x2, -0.1136149f);
  p = fmaf(p, x2, 0.786301f);
  float E = vc * p;
  float t = 0.5f * v;
  return fmaf(t, E, t);
}

// ---- fused pre-pass: pack_w (blocks 0..511) | route (512..767) ----
// rmsnorm is GONE — folded into moe_mlp's A-fragment prologue.
__global__ __launch_bounds__(256) void fused_pre(
    const float* __restrict__ W1, const float* __restrict__ W2,
    ushort_t* __restrict__ w1f, ushort_t* __restrict__ w2f,
    const int* __restrict__ eids, int* __restrict__ cnt,
    int* __restrict__ lists) {
  __shared__ ushort_t tile[64][130];
  __shared__ int lcnt[8], lbase[8];
  int bid = blockIdx.x;
  int t = threadIdx.x;

  if (bid < 512) {
    // ---- pack W1/W2 into MFMA fragment order via LDS tile ----
    // W1 (K=32 frags): unit = e*32768 + ch*1024 + kk*128 + nt*64 + lane;
    //   elem j = W1[e][kk*32+quad*8+j][ch*32+nt*16+l16]
    // W2 (half-interleaved, A-operand of concat-K32 GEMM2):
    //   unit U = ((e*32+ch)*16+ct)*64 + lane ;
    //   elem j   = W2[e][ch*32 +  0 + quad*4+j][ct*16+l16]
    //   elem 4+j = W2[e][ch*32 + 16 + quad*4+j][ct*16+l16]
    int b = bid;
    int isW2 = b >= 256;
    const float* src; ushort_t* dst; int e, kt, wt, rs;
    if (!isW2) { e = b >> 5; kt = (b >> 3) & 3; wt = b & 7; src = W1; dst = w1f; rs = 1024; }
    else { b -= 256; e = b >> 5; kt = (b >> 1) & 15; wt = b & 1; src = W2; dst = w2f; rs = 256; }
    int k0 = kt * 64, c0 = wt * 128;
    const float* sb = src + ((size_t)e << 18) + (size_t)k0 * rs + c0;
#pragma unroll
    for (int i = 0; i < 8; ++i) {
      int f = i * 1024 + t * 4;          // [0,8192)
      int r = f >> 7, c = f & 127;
      float4 v = *reinterpret_cast<const float4*>(sb + (size_t)r * rs + c);
      ushort2 lo, hi;
      lo.x = f2bf(v.x); lo.y = f2bf(v.y); hi.x = f2bf(v.z); hi.y = f2bf(v.w);
      *reinterpret_cast<ushort2*>(&tile[r][c]) = lo;
      *reinterpret_cast<ushort2*>(&tile[r][c + 2]) = hi;
    }
    __syncthreads();
    int lane = t & 63, l16 = lane & 15, quad = lane >> 4;
    int wave = t >> 6;
    if (!isW2) {
#pragma unroll
      for (int p = 0; p < 4; ++p) {
        int u = p * 256 + t;               // [0,1024)
        int kk2 = (u >> 9) & 1;
        int rr = kk2 * 32 + quad * 8;
        int nt = (u >> 6) & 1, chL = (u >> 7) & 3;
        int cc = chL * 32 + nt * 16 + l16;
        u16x8 o;
#pragma unroll
        for (int j = 0; j < 8; ++j) o[j] = tile[rr + j][cc];
        size_t U = ((size_t)e * 32768) + (size_t)(wt * 4 + chL) * 1024 + (kt * 2 + kk2) * 128 + nt * 64 + lane;
        *reinterpret_cast<u16x8*>(dst + U * 8) = o;
      }
    } else {
#pragma unroll
      for (int p = 0; p < 4; ++p) {
        int u = p * 4 + wave;              // [0,16): chL(2) x ctL(8)
        int chL = u >> 3, ctL = u & 7;
        int cc = ctL * 16 + l16;
        u16x8 o;
#pragma unroll
        for (int j = 0; j < 4; ++j) o[j] = tile[chL * 32 + quad * 4 + j][cc];
#pragma unroll
        for (int j = 0; j < 4; ++j) o[4 + j] = tile[chL * 32 + 16 + quad * 4 + j][cc];
        size_t U = (((size_t)(e * 32 + kt * 2 + chL) * 16) + (wt * 8 + ctL)) * 64 + lane;
        *reinterpret_cast<u16x8*>(dst + U * 8) = o;
      }
    }
  } else {
    // ---- route (t,k) pairs into per-expert lists ----
    if (t < 8) lcnt[t] = 0;
    __syncthreads();
    int p = (bid - 512) * 256 + t;
    int e = eids[p];
    int lpos = atomicAdd(&lcnt[e], 1);
    __syncthreads();
    if (t < 8) lbase[t] = atomicAdd(&cnt[t], lcnt[t]);
    __syncthreads();
    lists[e * 65536 + lbase[e] + lpos] = p;
  }
}

// ---- fused expert MLP (RMSNorm folded in) ----
// 256-thread blocks, 4 waves x 32 tokens (mt=2): mt=2's halved LDS-read-per-
// token (r4-validated traffic model) WITH r3's multi-block latency hiding:
// grid 520 = 8x65 (2.03 blocks/CU, fine tail granularity), launch_bounds
// (256,2) -> 2 blocks/CU co-resident (LDS 96KB <= 160, regs ~124+128 fits
// 2 waves/SIMD — proven by r4's VGPR_Count=124 on this same inner loop).
// Prologue: per-token RMS via quad-group shfl_xor(16/32) — x read directly,
// no separate rmsnorm pass (was ~90us of serial pre-work).
__global__ __launch_bounds__(256, 2) void moe_mlp(
    const float* __restrict__ x,       // [32768][256] f32
    const float* __restrict__ rw,      // [256] rms weight
    const ushort_t* __restrict__ w1f,  // [8][32][8][2][64][8]
    const ushort_t* __restrict__ w2f,  // [8][32][16][64][8]
    const float* __restrict__ b1,      // [8][1024]
    const float* __restrict__ b2,      // [8][256]
    const int* __restrict__ cnt,       // [8]
    const int* __restrict__ lists,     // [8][65536]
    float* __restrict__ out)           // [65536][256]
{
  __shared__ __align__(16) ushort_t w1b[2][8192];   // 2 x 16KB
  __shared__ __align__(16) ushort_t w2b[8192];      // 1 x 16KB

  // bijective XCD swizzle; gridDim.x = 520 = 8*65 exactly
  int cpx = gridDim.x >> 3;
  int flat = (blockIdx.x & 7) * cpx + (blockIdx.x >> 3);

  int e = -1, tile = 0, accum = 0, n_e = 0;
#pragma unroll
  for (int i = 0; i < 8; ++i) {
    int c = cnt[i];
    int ti = (c + 127) >> 7;
    if (e < 0 && flat < accum + ti) { e = i; tile = flat - accum; n_e = c; }
    accum += ti;
  }
  if (e < 0) return;
  int start = tile * 128;

  int tid = threadIdx.x;
  int wave = tid >> 6, lane = tid & 63, l16 = lane & 15, quad = lane >> 4;

  const ushort_t* w1e = w1f + ((size_t)e << 18);
  const ushort_t* w2e = w2f + ((size_t)e << 18);
  const int* le = lists + e * 65536;

  // stage W1(0) into buffer 0 (16 x 1KB units across 4 waves)
#pragma unroll
  for (int j = 0; j < 4; ++j) {
    int p = j * 4 + wave;
    g2l16(w1e + p * 512 + lane * 8, &w1b[0][p * 512]);
  }

  // ---- A fragments with in-prologue RMSNorm ----
  // Token row (256 f32) is spread over the 4 quad-lanes of this l16 group
  // (64 floats each: k = kk*32 + quad*8 + j). Pass 1: sum-of-squares +
  // quad-group reduce via shfl_xor(16,32). Pass 2 (L1-hot): reload, scale
  // by inv*rw, pack to bf16 A-frags.
  bf16x8 afr[2][8];
  {
    int gi0 = start + wave * 32 + l16;
    int pr0 = le[(gi0 < n_e) ? gi0 : 0];
    int pr1 = le[(gi0 + 16 < n_e) ? gi0 + 16 : 0];
    const float* xr0 = x + (size_t)(pr0 >> 1) * 256 + quad * 8;
    const float* xr1 = x + (size_t)(pr1 >> 1) * 256 + quad * 8;
    float s0 = 0.f, s1 = 0.f;
#pragma unroll
    for (int kk = 0; kk < 8; ++kk) {
      float4 a = *reinterpret_cast<const float4*>(xr0 + kk * 32);
      float4 b = *reinterpret_cast<const float4*>(xr0 + kk * 32 + 4);
      s0 += a.x * a.x + a.y * a.y + a.z * a.z + a.w * a.w;
      s0 += b.x * b.x + b.y * b.y + b.z * b.z + b.w * b.w;
      float4 c = *reinterpret_cast<const float4*>(xr1 + kk * 32);
      float4 d = *reinterpret_cast<const float4*>(xr1 + kk * 32 + 4);
      s1 += c.x * c.x + c.y * c.y + c.z * c.z + c.w * c.w;
      s1 += d.x * d.x + d.y * d.y + d.z * d.z + d.w * d.w;
    }
    s0 += __shfl_xor(s0, 16); s0 += __shfl_xor(s0, 32);
    s1 += __shfl_xor(s1, 16); s1 += __shfl_xor(s1, 32);
    float inv0 = rsqrtf(s0 * (1.0f / 256.0f) + RMS_EPS);
    float inv1 = rsqrtf(s1 * (1.0f / 256.0f) + RMS_EPS);
#pragma unroll
    for (int kk = 0; kk < 8; ++kk) {
      float4 wa = *reinterpret_cast<const float4*>(rw + kk * 32 + quad * 8);
      float4 wb = *reinterpret_cast<const float4*>(rw + kk * 32 + quad * 8 + 4);
      float4 a = *reinterpret_cast<const float4*>(xr0 + kk * 32);
      float4 b = *reinterpret_cast<const float4*>(xr0 + kk * 32 + 4);
      u16x8 t0;
      t0[0] = f2bf(a.x * inv0 * wa.x); t0[1] = f2bf(a.y * inv0 * wa.y);
      t0[2] = f2bf(a.z * inv0 * wa.z); t0[3] = f2bf(a.w * inv0 * wa.w);
      t0[4] = f2bf(b.x * inv0 * wb.x); t0[5] = f2bf(b.y * inv0 * wb.y);
      t0[6] = f2bf(b.z * inv0 * wb.z); t0[7] = f2bf(b.w * inv0 * wb.w);
      afr[0][kk] = __builtin_bit_cast(bf16x8, t0);
      float4 c = *reinterpret_cast<const float4*>(xr1 + kk * 32);
      float4 d = *reinterpret_cast<const float4*>(xr1 + kk * 32 + 4);
      u16x8 t1;
      t1[0] = f2bf(c.x * inv1 * wa.x); t1[1] = f2bf(c.y * inv1 * wa.y);
      t1[2] = f2bf(c.z * inv1 * wa.z); t1[3] = f2bf(c.w * inv1 * wa.w);
      t1[4] = f2bf(d.x * inv1 * wb.x); t1[5] = f2bf(d.y * inv1 * wb.y);
      t1[6] = f2bf(d.z * inv1 * wb.z); t1[7] = f2bf(d.w * inv1 * wb.w);
      afr[1][kk] = __builtin_bit_cast(bf16x8, t1);
    }
  }

  f32x4 acc[2][16];
#pragma unroll
  for (int mt = 0; mt < 2; ++mt)
#pragma unroll
    for (int ct = 0; ct < 16; ++ct) acc[mt][ct] = (f32x4){0.f, 0.f, 0.f, 0.f};

  const float* b1e = b1 + e * 1024;

  for (int ch = 0; ch < 32; ++ch) {
    int cur = ch & 1;
    __syncthreads();   // W1(ch) staged+visible; w2b free (GEMM2(ch-1) done)

    // stage W2(ch) -> single buffer (lands under GEMM1+GELU)
    {
      const ushort_t* n2 = w2e + ch * 8192;
#pragma unroll
      for (int j = 0; j < 4; ++j) {
        int p = j * 4 + wave;
        g2l16(n2 + p * 512 + lane * 8, &w2b[p * 512]);
      }
    }
    // stage W1(ch+1) -> alternate buffer
    if (ch + 1 < 32) {
      const ushort_t* n1 = w1e + (ch + 1) * 8192;
#pragma unroll
      for (int j = 0; j < 4; ++j) {
        int p = j * 4 + wave;
        g2l16(n1 + p * 512 + lane * 8, &w1b[cur ^ 1][p * 512]);
      }
    }

    // GEMM1 (swapped): hT ; 4 independent chains x 8 deep; each W1 frag
    // read (b128) feeds 2 MFMAs (mt=2 traffic amortization)
    const ushort_t* l1 = w1b[cur];
    f32x4 ht00 = (f32x4){0.f, 0.f, 0.f, 0.f};
    f32x4 ht01 = (f32x4){0.f, 0.f, 0.f, 0.f};
    f32x4 ht10 = (f32x4){0.f, 0.f, 0.f, 0.f};
    f32x4 ht11 = (f32x4){0.f, 0.f, 0.f, 0.f};
#pragma unroll
    for (int kk = 0; kk < 8; ++kk) {
      bf16x8 wA = *reinterpret_cast<const bf16x8*>(l1 + ((kk * 2 + 0) * 64 + lane) * 8);
      bf16x8 wB = *reinterpret_cast<const bf16x8*>(l1 + ((kk * 2 + 1) * 64 + lane) * 8);
      ht00 = mfma32(wA, afr[0][kk], ht00);
      ht10 = mfma32(wA, afr[1][kk], ht10);
      ht01 = mfma32(wB, afr[0][kk], ht01);
      ht11 = mfma32(wB, afr[1][kk], ht11);
    }

    // biases loaded late (short live range)
    int w0 = ch * 32;
    f32x4 bia0 = *reinterpret_cast<const f32x4*>(b1e + w0 + quad * 4);
    f32x4 bia1 = *reinterpret_cast<const f32x4*>(b1e + w0 + 16 + quad * 4);

    // GELU + bf16 pack in registers. elems 0-3 = nt0 half (w=w0+quad*4+r),
    // elems 4-7 = nt1 half — matches W2 frag interleave (r2-verified).
    u16x8 hp0, hp1;
#pragma unroll
    for (int rr = 0; rr < 4; ++rr) {
      hp0[rr]     = f2bf(gelu1(ht00[rr] + bia0[rr]));
      hp0[4 + rr] = f2bf(gelu1(ht01[rr] + bia1[rr]));
      hp1[rr]     = f2bf(gelu1(ht10[rr] + bia0[rr]));
      hp1[4 + rr] = f2bf(gelu1(ht11[rr] + bia1[rr]));
    }
    bf16x8 hF0 = __builtin_bit_cast(bf16x8, hp0);
    bf16x8 hF1 = __builtin_bit_cast(bf16x8, hp1);

    __syncthreads();   // W2(ch) staged+visible (all waves)

    // GEMM2: yT[32 tok x 256] += W2^T . hT via K=32 MFMA; each W2 frag
    // read feeds 2 MFMAs
#pragma unroll
    for (int ct = 0; ct < 16; ++ct) {
      bf16x8 wq = *reinterpret_cast<const bf16x8*>(w2b + (ct * 64 + lane) * 8);
      acc[0][ct] = mfma32(wq, hF0, acc[0][ct]);
      acc[1][ct] = mfma32(wq, hF1, acc[1][ct]);
    }
  }

  // epilogue: +b2, masked float4 store; pr re-read from lists (not kept live)
  const float* b2e = b2 + e * 256;
#pragma unroll
  for (int mt = 0; mt < 2; ++mt) {
    int gi = start + wave * 32 + mt * 16 + l16;
    if (gi < n_e) {
      int pr = le[gi];
      float* orow = out + (size_t)pr * 256;
#pragma unroll
      for (int ct = 0; ct < 16; ++ct) {
        f32x4 bv = *reinterpret_cast<const f32x4*>(b2e + ct * 16 + quad * 4);
        f32x4 o = acc[mt][ct] + bv;
        *reinterpret_cast<f32x4*>(orow + ct * 16 + quad * 4) = o;
      }
    }
  }
}

extern "C" void kernel_launch(void* const* d_in, const int* in_sizes, int n_in,
                              void* d_out, int out_size, void* d_ws, size_t ws_size,
                              hipStream_t stream) {
  const float* x  = (const float*)d_in[0];
  const float* rw = (const float*)d_in[1];
  const float* W1 = (const float*)d_in[2];
  const float* b1 = (const float*)d_in[3];
  const float* W2 = (const float*)d_in[4];
  const float* b2 = (const float*)d_in[5];
  const int* eids = (const int*)d_in[6];
  float* out = (float*)d_out;

  char* ws = (char*)d_ws;
  ushort_t* w1f = (ushort_t*)(ws);              //  4,194,304 B
  ushort_t* w2f = (ushort_t*)(ws + 4194304);    //  4,194,304 B
  int* cnt      = (int*)(ws + 8388608);         //  256 B (8 used)
  int* lists    = (int*)(ws + 8388864);         //  2,097,152 B

  hipMemsetAsync(cnt, 0, 8 * sizeof(int), stream);
  // pre-pass: pack_w (512 blocks) + route (256 blocks); rmsnorm folded into moe
  fused_pre<<<768, 256, 0, stream>>>(W1, W2, w1f, w2f, eids, cnt, lists);
  // max tiles = sum_e ceil(c_e/128) <= 65536/128 + 7 = 519 <= 520 (= 8*65)
  moe_mlp<<<520, 256, 0, stream>>>(x, rw, w1f, w2f, b1, b2, cnt, lists, out);
}

// Round 6
// 219.501 us; speedup vs baseline: 1.3274x; 1.2223x over previous
//
#include <hip/hip_runtime.h>
#include <cstdint>

typedef unsigned short ushort_t;
typedef __bf16 bf16x8 __attribute__((ext_vector_type(8)));
typedef ushort_t u16x8 __attribute__((ext_vector_type(8)));
typedef float f32x4 __attribute__((ext_vector_type(4)));
typedef uint32_t u32x4 __attribute__((ext_vector_type(4)));

#define RMS_EPS 1.1920928955078125e-07f
// B=8 T=4096 C=256 Wh=1024 E=8 K=2 ; tokens NT=32768, pairs NP=65536

__device__ __forceinline__ ushort_t f2bf(float f) {
  uint32_t u = __builtin_bit_cast(uint32_t, f);
  u += 0x7fffu + ((u >> 16) & 1u);   // RNE
  return (ushort_t)(u >> 16);
}

__device__ __forceinline__ void g2l16(const ushort_t* g, ushort_t* l) {
  __builtin_amdgcn_global_load_lds(
      (const __attribute__((address_space(1))) uint32_t*)g,
      (__attribute__((address_space(3))) uint32_t*)l, 16, 0, 0);
}

__device__ __forceinline__ f32x4 mfma32(bf16x8 a, bf16x8 b, f32x4 c) {
  return __builtin_amdgcn_mfma_f32_16x16x32_bf16(a, b, c, 0, 0, 0);
}

// GELU via odd-poly erf approx (validated r3-r5, absmax 8.0 vs thr 41.6)
__device__ __forceinline__ float gelu1(float v) {
  float vc = fminf(fmaxf(v, -2.9f), 2.9f);   // v_med3
  float x2 = vc * vc;
  float p = fmaf(-0.000414256f, x2, 0.0107517f);
  p = fmaf(p, x2, -0.1136149f);
  p = fmaf(p, x2, 0.786301f);
  float E = vc * p;
  float t = 0.5f * v;
  return fmaf(t, E, t);
}

// ---- fused pre-pass (r4 known-good): rmsnorm (0..8191) | pack_w
//      (8192..8703) | route (8704..8959) ----
__global__ __launch_bounds__(256) void fused_pre(
    const float* __restrict__ x, const float* __restrict__ rw,
    ushort_t* __restrict__ xn,
    const float* __restrict__ W1, const float* __restrict__ W2,
    ushort_t* __restrict__ w1f, ushort_t* __restrict__ w2f,
    const int* __restrict__ eids, int* __restrict__ cnt,
    int* __restrict__ lists) {
  __shared__ ushort_t tile[64][130];
  __shared__ int lcnt[8], lbase[8];
  int bid = blockIdx.x;
  int t = threadIdx.x;

  if (bid < 8192) {
    // ---- RMSNorm + cast to bf16: one wave per token ----
    int token = bid * 4 + (t >> 6);
    int lane = t & 63;
    const float4* row = reinterpret_cast<const float4*>(x + (size_t)token * 256);
    float4 v = row[lane];
    float s = v.x * v.x + v.y * v.y + v.z * v.z + v.w * v.w;
#pragma unroll
    for (int off = 1; off < 64; off <<= 1) s += __shfl_xor(s, off);
    float inv = rsqrtf(s * (1.0f / 256.0f) + RMS_EPS);
    const float4* wr = reinterpret_cast<const float4*>(rw);
    float4 wv = wr[lane];
    ushort4 o;
    o.x = f2bf(v.x * inv * wv.x);
    o.y = f2bf(v.y * inv * wv.y);
    o.z = f2bf(v.z * inv * wv.z);
    o.w = f2bf(v.w * inv * wv.w);
    *reinterpret_cast<ushort4*>(xn + (size_t)token * 256 + lane * 4) = o;
  } else if (bid < 8704) {
    // ---- pack W1/W2 into MFMA fragment order via LDS tile ----
    // W1 (K=32 frags): unit = e*32768 + ch*1024 + kk*128 + nt*64 + lane;
    //   elem j = W1[e][kk*32+quad*8+j][ch*32+nt*16+l16]
    // W2 (half-interleaved, A-operand of concat-K32 GEMM2):
    //   unit U = ((e*32+ch)*16+ct)*64 + lane ;
    //   elem j   = W2[e][ch*32 +  0 + quad*4+j][ct*16+l16]
    //   elem 4+j = W2[e][ch*32 + 16 + quad*4+j][ct*16+l16]
    int b = bid - 8192;
    int isW2 = b >= 256;
    const float* src; ushort_t* dst; int e, kt, wt, rs;
    if (!isW2) { e = b >> 5; kt = (b >> 3) & 3; wt = b & 7; src = W1; dst = w1f; rs = 1024; }
    else { b -= 256; e = b >> 5; kt = (b >> 1) & 15; wt = b & 1; src = W2; dst = w2f; rs = 256; }
    int k0 = kt * 64, c0 = wt * 128;
    const float* sb = src + ((size_t)e << 18) + (size_t)k0 * rs + c0;
#pragma unroll
    for (int i = 0; i < 8; ++i) {
      int f = i * 1024 + t * 4;          // [0,8192)
      int r = f >> 7, c = f & 127;
      float4 v = *reinterpret_cast<const float4*>(sb + (size_t)r * rs + c);
      ushort2 lo, hi;
      lo.x = f2bf(v.x); lo.y = f2bf(v.y); hi.x = f2bf(v.z); hi.y = f2bf(v.w);
      *reinterpret_cast<ushort2*>(&tile[r][c]) = lo;
      *reinterpret_cast<ushort2*>(&tile[r][c + 2]) = hi;
    }
    __syncthreads();
    int lane = t & 63, l16 = lane & 15, quad = lane >> 4;
    int wave = t >> 6;
    if (!isW2) {
#pragma unroll
      for (int p = 0; p < 4; ++p) {
        int u = p * 256 + t;               // [0,1024)
        int kk2 = (u >> 9) & 1;
        int rr = kk2 * 32 + quad * 8;
        int nt = (u >> 6) & 1, chL = (u >> 7) & 3;
        int cc = chL * 32 + nt * 16 + l16;
        u16x8 o;
#pragma unroll
        for (int j = 0; j < 8; ++j) o[j] = tile[rr + j][cc];
        size_t U = ((size_t)e * 32768) + (size_t)(wt * 4 + chL) * 1024 + (kt * 2 + kk2) * 128 + nt * 64 + lane;
        *reinterpret_cast<u16x8*>(dst + U * 8) = o;
      }
    } else {
#pragma unroll
      for (int p = 0; p < 4; ++p) {
        int u = p * 4 + wave;              // [0,16): chL(2) x ctL(8)
        int chL = u >> 3, ctL = u & 7;
        int cc = ctL * 16 + l16;
        u16x8 o;
#pragma unroll
        for (int j = 0; j < 4; ++j) o[j] = tile[chL * 32 + quad * 4 + j][cc];
#pragma unroll
        for (int j = 0; j < 4; ++j) o[4 + j] = tile[chL * 32 + 16 + quad * 4 + j][cc];
        size_t U = (((size_t)(e * 32 + kt * 2 + chL) * 16) + (wt * 8 + ctL)) * 64 + lane;
        *reinterpret_cast<u16x8*>(dst + U * 8) = o;
      }
    }
  } else {
    // ---- route (t,k) pairs into per-expert lists ----
    if (t < 8) lcnt[t] = 0;
    __syncthreads();
    int p = (bid - 8704) * 256 + t;
    int e = eids[p];
    int lpos = atomicAdd(&lcnt[e], 1);
    __syncthreads();
    if (t < 8) lbase[t] = atomicAdd(&cnt[t], lcnt[t]);
    __syncthreads();
    lists[e * 65536 + lbase[e] + lpos] = p;
  }
}

// ---- fused expert MLP (r3 structure + counted-vmcnt pipeline) ----
// 64 pairs/block, 4 waves x 16 rows (r3's proven 120.7us occupancy point:
// ~80 VGPR + 64 AGPR -> 2-3 blocks/CU). Sync structure upgraded (T4):
//  - issue order per chunk, sched_barrier-pinned: bias(2) -> W2(4) -> W1next(4)
//  - mid barrier: s_waitcnt vmcnt(4) + raw s_barrier  => W2 retired (FIFO),
//    W1next's 4 loads stay IN FLIGHT across the barrier, land under GEMM2.
//  - top barrier: vmcnt(0) + raw s_barrier (GEMM1 needs W1(ch) now; no
//    ds_writes anywhere so no lgkmcnt drain needed).
//  - T5 setprio(1) around MFMA clusters (2 indep blocks/CU -> phase diversity).
__global__ __launch_bounds__(256, 3) void moe_mlp(
    const ushort_t* __restrict__ xn,   // [32768][256] bf16
    const ushort_t* __restrict__ w1f,  // [8][32][8][2][64][8]
    const ushort_t* __restrict__ w2f,  // [8][32][16][64][8]
    const float* __restrict__ b1,      // [8][1024]
    const float* __restrict__ b2,      // [8][256]
    const int* __restrict__ cnt,       // [8]
    const int* __restrict__ lists,     // [8][65536]
    float* __restrict__ out)           // [65536][256]
{
  __shared__ __align__(16) ushort_t w1b[2][8192];   // 2 x 16KB
  __shared__ __align__(16) ushort_t w2b[8192];      // 1 x 16KB

  // bijective XCD swizzle; gridDim.x = 1032 = 8*129 exactly
  int cpx = gridDim.x >> 3;
  int flat = (blockIdx.x & 7) * cpx + (blockIdx.x >> 3);

  int e = -1, tile = 0, accum = 0, n_e = 0;
#pragma unroll
  for (int i = 0; i < 8; ++i) {
    int c = cnt[i];
    int ti = (c + 63) >> 6;
    if (e < 0 && flat < accum + ti) { e = i; tile = flat - accum; n_e = c; }
    accum += ti;
  }
  if (e < 0) return;
  int start = tile * 64;

  int tid = threadIdx.x;
  int wave = tid >> 6, lane = tid & 63, l16 = lane & 15, quad = lane >> 4;

  const ushort_t* w1e = w1f + ((size_t)e << 18);
  const ushort_t* w2e = w2f + ((size_t)e << 18);
  const int* le = lists + e * 65536;

  // this wave's 16 token rows, register-resident
  int gi = start + wave * 16 + l16;
  int pr = le[(gi < n_e) ? gi : 0];

  // stage W1(0) into buffer 0 (16 x 1KB units across 4 waves)
#pragma unroll
  for (int j = 0; j < 4; ++j) {
    int p = j * 4 + wave;
    g2l16(w1e + p * 512 + lane * 8, &w1b[0][p * 512]);
  }

  // A fragments: 1 m-tile x full K=256, resident (32 VGPR)
  bf16x8 afr[8];
  {
    const u32x4* ar = reinterpret_cast<const u32x4*>(xn + (size_t)(pr >> 1) * 256);
#pragma unroll
    for (int kk = 0; kk < 8; ++kk)
      afr[kk] = __builtin_bit_cast(bf16x8, ar[kk * 4 + quad]);
  }

  f32x4 acc[16];
#pragma unroll
  for (int ct = 0; ct < 16; ++ct) acc[ct] = (f32x4){0.f, 0.f, 0.f, 0.f};

  const float* b1e = b1 + e * 1024;

  for (int ch = 0; ch < 32; ++ch) {
    int cur = ch & 1;
    // ---- top barrier: W1(ch) landed (own vmcnt), all waves off w2b ----
    asm volatile("s_waitcnt vmcnt(0)" ::: "memory");
    __builtin_amdgcn_s_barrier();
    __builtin_amdgcn_sched_barrier(0);

    // biases FIRST in vmem issue order (so mid vmcnt(4) retires them)
    int w0 = ch * 32;
    f32x4 bia0 = *reinterpret_cast<const f32x4*>(b1e + w0 + quad * 4);
    f32x4 bia1 = *reinterpret_cast<const f32x4*>(b1e + w0 + 16 + quad * 4);
    __builtin_amdgcn_sched_barrier(0);

    // stage W2(ch) -> single buffer   [vmem ops 3..6 this chunk]
    {
      const ushort_t* n2 = w2e + ch * 8192;
#pragma unroll
      for (int j = 0; j < 4; ++j) {
        int p = j * 4 + wave;
        g2l16(n2 + p * 512 + lane * 8, &w2b[p * 512]);
      }
    }
    __builtin_amdgcn_sched_barrier(0);
    // stage W1(ch+1) -> alternate buffer   [vmem ops 7..10; stay in flight
    // across the mid barrier — the whole point of this build]
    if (ch + 1 < 32) {
      const ushort_t* n1 = w1e + (ch + 1) * 8192;
#pragma unroll
      for (int j = 0; j < 4; ++j) {
        int p = j * 4 + wave;
        g2l16(n1 + p * 512 + lane * 8, &w1b[cur ^ 1][p * 512]);
      }
    }
    __builtin_amdgcn_sched_barrier(0);

    // GEMM1 (swapped): hT ; 2 independent chains x 8 deep
    const ushort_t* l1 = w1b[cur];
    f32x4 ht0 = (f32x4){0.f, 0.f, 0.f, 0.f};
    f32x4 ht1 = (f32x4){0.f, 0.f, 0.f, 0.f};
    __builtin_amdgcn_s_setprio(1);
#pragma unroll
    for (int kk = 0; kk < 8; ++kk) {
      bf16x8 wA = *reinterpret_cast<const bf16x8*>(l1 + ((kk * 2 + 0) * 64 + lane) * 8);
      bf16x8 wB = *reinterpret_cast<const bf16x8*>(l1 + ((kk * 2 + 1) * 64 + lane) * 8);
      ht0 = mfma32(wA, afr[kk], ht0);
      ht1 = mfma32(wB, afr[kk], ht1);
    }
    __builtin_amdgcn_s_setprio(0);

    // GELU + bf16 pack in registers. elems 0-3 = nt0 half, 4-7 = nt1 half
    // — matches W2 frag interleave (r2-verified).
    u16x8 hp;
#pragma unroll
    for (int rr = 0; rr < 4; ++rr) {
      hp[rr]     = f2bf(gelu1(ht0[rr] + bia0[rr]));
      hp[4 + rr] = f2bf(gelu1(ht1[rr] + bia1[rr]));
    }
    bf16x8 hF = __builtin_bit_cast(bf16x8, hp);

    // ---- mid barrier: W2(ch) retired (FIFO: bias2,W2x4 are the oldest 6);
    // W1(ch+1)'s 4 loads remain outstanding across the barrier ----
    if (ch < 31) {
      asm volatile("s_waitcnt vmcnt(4)" ::: "memory");
    } else {
      asm volatile("s_waitcnt vmcnt(0)" ::: "memory");
    }
    __builtin_amdgcn_s_barrier();
    __builtin_amdgcn_sched_barrier(0);

    // GEMM2: yT[16 tok x 256] += W2^T . hT via K=32 MFMA; 16 indep accs
    __builtin_amdgcn_s_setprio(1);
#pragma unroll
    for (int ct = 0; ct < 16; ++ct) {
      bf16x8 wq = *reinterpret_cast<const bf16x8*>(w2b + (ct * 64 + lane) * 8);
      acc[ct] = mfma32(wq, hF, acc[ct]);
    }
    __builtin_amdgcn_s_setprio(0);
  }

  // epilogue: +b2, masked float4 store (4 consecutive cols per lane)
  const float* b2e = b2 + e * 256;
  if (gi < n_e) {
    float* orow = out + (size_t)pr * 256;
#pragma unroll
    for (int ct = 0; ct < 16; ++ct) {
      f32x4 bv = *reinterpret_cast<const f32x4*>(b2e + ct * 16 + quad * 4);
      f32x4 o = acc[ct] + bv;
      *reinterpret_cast<f32x4*>(orow + ct * 16 + quad * 4) = o;
    }
  }
}

extern "C" void kernel_launch(void* const* d_in, const int* in_sizes, int n_in,
                              void* d_out, int out_size, void* d_ws, size_t ws_size,
                              hipStream_t stream) {
  const float* x  = (const float*)d_in[0];
  const float* rw = (const float*)d_in[1];
  const float* W1 = (const float*)d_in[2];
  const float* b1 = (const float*)d_in[3];
  const float* W2 = (const float*)d_in[4];
  const float* b2 = (const float*)d_in[5];
  const int* eids = (const int*)d_in[6];
  float* out = (float*)d_out;

  char* ws = (char*)d_ws;
  ushort_t* xn  = (ushort_t*)(ws);              // 16,777,216 B
  ushort_t* w1f = (ushort_t*)(ws + 16777216);   //  4,194,304 B
  ushort_t* w2f = (ushort_t*)(ws + 20971520);   //  4,194,304 B
  int* cnt      = (int*)(ws + 25165824);        //  256 B (8 used)
  int* lists    = (int*)(ws + 25166080);        //  2,097,152 B

  hipMemsetAsync(cnt, 0, 8 * sizeof(int), stream);
  // one fused pre-pass dispatch: rmsnorm (8192) + pack_w (512) + route (256)
  fused_pre<<<8960, 256, 0, stream>>>(x, rw, xn, W1, W2, w1f, w2f, eids, cnt, lists);
  // max tiles = sum_e ceil(c_e/64) <= 65536/64 + 8 = 1032 (= 8*129)
  moe_mlp<<<1032, 256, 0, stream>>>(xn, w1f, w2f, b1, b2, cnt, lists, out);
}